// Round 1
// 525.312 us; speedup vs baseline: 1.2476x; 1.2476x over previous
//
#include <hip/hip_runtime.h>
#include <hip/hip_bf16.h>
#include <stdint.h>

// ---------------------------------------------------------------------------
// LoRALinear (fp32 in / fp32 out):
//   C[M,N] = X[M,K] @ W[N,K]^T + bias[N] + 2.0 * (X @ A[R,K]^T) @ B[N,R]^T
// M=8192, N=4096, K=4096, R=16.
//
// Round-4: replace the m97-structure 128^2 GEMM (698 TF, MfmaUtil 32%,
// 8-way LDS bank conflicts) with a 256^2 / 8-wave / BK=32 pipeline:
//   - fragment-PACKED bf16 operands in workspace (16x32 MFMA blocks laid out
//     in lane order) -> global_load_lds staging is linear, ds_read_b128 is
//     64 consecutive 16B chunks -> zero bank conflicts, no addr VALU in loop
//   - 4-deep circular LDS buffer (128 KiB), prefetch distance 3 tiles
//   - counted s_waitcnt vmcnt(8) once per K-tile (never 0 in the loop),
//     raw s_barrier (no compiler vmcnt(0) drain), lgkmcnt(0)+sched_barrier
//     before each 16-MFMA cluster, s_setprio(1) around MFMAs
//   - bijective XCD swizzle over the 512-workgroup grid
// P2/P3 fallback paths (smaller workspace) retained from round-3.
// ---------------------------------------------------------------------------

typedef __bf16 bf16x8 __attribute__((ext_vector_type(8)));
typedef __bf16 bf16x4 __attribute__((ext_vector_type(4)));
typedef float f32x4 __attribute__((ext_vector_type(4)));

#define LORA_R 16

__device__ __forceinline__ void async_copy16(const void* g, void* l) {
  // global -> LDS direct copy, 16 B/lane; LDS dest = wave-uniform base + lane*16.
  __builtin_amdgcn_global_load_lds(
      (const __attribute__((address_space(1))) void*)g,
      (__attribute__((address_space(3))) void*)l, 16, 0, 0);
}

// ---------------------------------------------------------------------------
// Packed operand layout: matrix of R rows x K cols (row-major source) is
// stored as blocks of 16 rows x 32 cols. Block (rb, kb) lives at byte offset
// (rb*(K/32)+kb)*1024. Within a block, lane l's 16 B = 8 bf16 elements
//   row = rb*16 + (l & 15),  k = kb*32 + (l>>4)*8 + e
// which is exactly the mfma_f32_16x16x32_bf16 A/B fragment layout.
// ---------------------------------------------------------------------------

// Xp = packed bf16(X). grid (K/128, M/16), 256 thr (4 waves; 1 block each).
__global__ __launch_bounds__(256) void pack_x_kernel(
    const float* __restrict__ X, __hip_bfloat16* __restrict__ Xp, int K) {
  const int lane = threadIdx.x & 63;
  const int wave = threadIdx.x >> 6;
  const int nkb = K >> 5;
  const int kb = blockIdx.x * 4 + wave;
  const int mb = blockIdx.y;
  const int row = (mb << 4) + (lane & 15);
  const int col = (kb << 5) + ((lane >> 4) << 3);
  const float* src = X + (size_t)row * K + col;
  f32x4 v0 = *(const f32x4*)src;
  f32x4 v1 = *(const f32x4*)(src + 4);
  bf16x8 o;
#pragma unroll
  for (int j = 0; j < 4; ++j) { o[j] = (__bf16)v0[j]; o[4 + j] = (__bf16)v1[j]; }
  *(bf16x8*)((char*)Xp + ((size_t)(mb * nkb + kb) << 10) + (lane << 4)) = o;
}

// Wp = packed bf16(W + 2*B@A). grid (K/128, N/16), 256 thr.
__global__ __launch_bounds__(256) void foldpack_w_kernel(
    const float* __restrict__ W, const float* __restrict__ A,
    const float* __restrict__ Bl, __hip_bfloat16* __restrict__ Wp, int K) {
  const int lane = threadIdx.x & 63;
  const int wave = threadIdx.x >> 6;
  const int nkb = K >> 5;
  const int kb = blockIdx.x * 4 + wave;
  const int nb = blockIdx.y;
  const int n = (nb << 4) + (lane & 15);
  const int col = (kb << 5) + ((lane >> 4) << 3);
  float res[8];
  {
    f32x4 w0 = *(const f32x4*)(W + (size_t)n * K + col);
    f32x4 w1 = *(const f32x4*)(W + (size_t)n * K + col + 4);
#pragma unroll
    for (int j = 0; j < 4; ++j) { res[j] = w0[j]; res[4 + j] = w1[j]; }
  }
#pragma unroll
  for (int r = 0; r < LORA_R; ++r) {
    const float b2 = 2.0f * Bl[n * LORA_R + r];  // SCALING = 2.0
    f32x4 a0 = *(const f32x4*)(A + (size_t)r * K + col);
    f32x4 a1 = *(const f32x4*)(A + (size_t)r * K + col + 4);
#pragma unroll
    for (int j = 0; j < 4; ++j) { res[j] += b2 * a0[j]; res[4 + j] += b2 * a1[j]; }
  }
  bf16x8 o;
#pragma unroll
  for (int j = 0; j < 8; ++j) o[j] = (__bf16)res[j];
  *(bf16x8*)((char*)Wp + ((size_t)(nb * nkb + kb) << 10) + (lane << 4)) = o;
}

// ---------------------------------------------------------------------------
// 256x256 tile GEMM over packed operands. 512 threads = 8 waves (2 M x 4 N),
// each wave owns a 128x64 sub-tile as acc[8][4] (16x16 frags). BK=32.
// LDS: 4 circular buffers x (16KB A + 16KB B) = 128 KiB.
// Per K-tile: 4 global_load_lds/wave (A site0, A site1, B site0, B site1),
// 2 phases x {8/4 ds_read_b128, 2 stage-issues, barrier, lgkmcnt(0),
// setprio(1), 16 MFMA, setprio(0), barrier}; vmcnt(8) at end-of-tile phase.
// Prefetch distance 3 tiles: stage t+3 while computing t (slot (t+3)&3 was
// last read in tile t-1, whose reads completed before its trailing barrier).
// ---------------------------------------------------------------------------
__global__ __launch_bounds__(512, 2) void gemm_pipelined(
    const __hip_bfloat16* __restrict__ Xp,  // packed [M/16][K/32] blocks
    const __hip_bfloat16* __restrict__ Wp,  // packed [N/16][K/32] blocks
    const float* __restrict__ bias,
    float* __restrict__ Out, int M, int N, int K) {
  __shared__ __align__(16) char lds[131072];

  const int tid = threadIdx.x;
  const int lane = tid & 63;
  const int wave = tid >> 6;
  const int wm = wave >> 2;  // 0..1
  const int wn = wave & 3;   // 0..3

  // Bijective XCD-aware swizzle (gridDim.x = 512, % 8 == 0).
  const int nwg = gridDim.x;
  const int bid = blockIdx.x;
  const int swz = (bid & 7) * (nwg >> 3) + (bid >> 3);
  const int ntn = N >> 8;           // tiles along N = 16
  const int tm = swz / ntn;
  const int tn = swz - tm * ntn;

  const int nkb = K >> 5;           // K-tiles (BK=32) = 128
  const int nt = nkb;

  // Per-lane global staging bases: site s adds s*8*nkb*1024; tile kb adds kb*1024.
  const char* aSrc = (const char*)Xp +
      ((size_t)((tm << 4) + wave) * nkb << 10) + (lane << 4);
  const char* bSrc = (const char*)Wp +
      ((size_t)((tn << 4) + wave) * nkb << 10) + (lane << 4);
  const size_t siteStride = (size_t)8 * nkb << 10;

  // Wave-uniform LDS staging dests (slot s*8+wave): buf*32768 [+16384 B] + ...
  char* ldsA = lds + (wave << 10);
  char* ldsB = lds + 16384 + (wave << 10);
  // Fragment-read bases (64 consecutive 16B chunks per block -> 0 conflicts).
  const char* ldsRdA = lds + (wm << 13) + (lane << 4);           // wm*8 blocks
  const char* ldsRdB = lds + 16384 + (wn << 12) + (lane << 4);   // wn*4 blocks

  f32x4 acc[8][4];
#pragma unroll
  for (int i = 0; i < 8; ++i)
#pragma unroll
    for (int j = 0; j < 4; ++j) acc[i][j] = (f32x4){0.f, 0.f, 0.f, 0.f};

  // Prologue: stage tiles 0,1,2 into bufs 0,1,2 (12 loads/wave); tile 0 landed
  // after vmcnt(8) (4 oldest of 12 retired).
#pragma unroll
  for (int pt = 0; pt < 3; ++pt) {
    const int bo = pt << 15;
    async_copy16(aSrc + ((size_t)pt << 10), ldsA + bo);
    async_copy16(aSrc + siteStride + ((size_t)pt << 10), ldsA + bo + 8192);
    async_copy16(bSrc + ((size_t)pt << 10), ldsB + bo);
    async_copy16(bSrc + siteStride + ((size_t)pt << 10), ldsB + bo + 8192);
  }
  asm volatile("s_waitcnt vmcnt(8)" ::: "memory");
  __builtin_amdgcn_s_barrier();

  bf16x8 af[4], bv[4];
  for (int t = 0; t < nt - 3; ++t) {
    const int buf = t & 3;
    const int pb = (t + 3) & 3;
    const size_t kOff = (size_t)(t + 3) << 10;
    const char* aP = ldsRdA + (buf << 15);
    const char* bP = ldsRdB + (buf << 15);
    // ---------------- phase 0: m-frags 0-3 x n-frags 0-3 ----------------
#pragma unroll
    for (int i = 0; i < 4; ++i) af[i] = *(const bf16x8*)(aP + (i << 10));
#pragma unroll
    for (int i = 0; i < 4; ++i) bv[i] = *(const bf16x8*)(bP + (i << 10));
    async_copy16(aSrc + kOff, ldsA + (pb << 15));
    async_copy16(aSrc + siteStride + kOff, ldsA + (pb << 15) + 8192);
    __builtin_amdgcn_s_barrier();
    asm volatile("s_waitcnt lgkmcnt(0)" ::: "memory");
    __builtin_amdgcn_sched_barrier(0);
    __builtin_amdgcn_s_setprio(1);
#pragma unroll
    for (int mi = 0; mi < 4; ++mi)
#pragma unroll
      for (int ni = 0; ni < 4; ++ni)
        acc[mi][ni] = __builtin_amdgcn_mfma_f32_16x16x32_bf16(
            af[mi], bv[ni], acc[mi][ni], 0, 0, 0);
    __builtin_amdgcn_s_setprio(0);
    __builtin_amdgcn_s_barrier();
    // ---------------- phase 1: m-frags 4-7 x n-frags 0-3 ----------------
#pragma unroll
    for (int i = 0; i < 4; ++i) af[i] = *(const bf16x8*)(aP + 4096 + (i << 10));
    async_copy16(bSrc + kOff, ldsB + (pb << 15));
    async_copy16(bSrc + siteStride + kOff, ldsB + (pb << 15) + 8192);
    // Counted wait: tiles t+2,t+3 (8 loads) may stay in flight; tile t+1 landed.
    asm volatile("s_waitcnt vmcnt(8)" ::: "memory");
    __builtin_amdgcn_s_barrier();
    asm volatile("s_waitcnt lgkmcnt(0)" ::: "memory");
    __builtin_amdgcn_sched_barrier(0);
    __builtin_amdgcn_s_setprio(1);
#pragma unroll
    for (int mi = 0; mi < 4; ++mi)
#pragma unroll
      for (int ni = 0; ni < 4; ++ni)
        acc[4 + mi][ni] = __builtin_amdgcn_mfma_f32_16x16x32_bf16(
            af[mi], bv[ni], acc[4 + mi][ni], 0, 0, 0);
    __builtin_amdgcn_s_setprio(0);
    __builtin_amdgcn_s_barrier();
  }
  // Drain remaining staging, then last 3 tiles (no writes in flight).
  asm volatile("s_waitcnt vmcnt(0)" ::: "memory");
  __builtin_amdgcn_s_barrier();
  for (int t = nt - 3; t < nt; ++t) {
    const int buf = t & 3;
    const char* aP = ldsRdA + (buf << 15);
    const char* bP = ldsRdB + (buf << 15);
#pragma unroll
    for (int i = 0; i < 4; ++i) af[i] = *(const bf16x8*)(aP + (i << 10));
#pragma unroll
    for (int i = 0; i < 4; ++i) bv[i] = *(const bf16x8*)(bP + (i << 10));
#pragma unroll
    for (int mi = 0; mi < 4; ++mi)
#pragma unroll
      for (int ni = 0; ni < 4; ++ni)
        acc[mi][ni] = __builtin_amdgcn_mfma_f32_16x16x32_bf16(
            af[mi], bv[ni], acc[mi][ni], 0, 0, 0);
#pragma unroll
    for (int i = 0; i < 4; ++i) af[i] = *(const bf16x8*)(aP + 4096 + (i << 10));
#pragma unroll
    for (int mi = 0; mi < 4; ++mi)
#pragma unroll
      for (int ni = 0; ni < 4; ++ni)
        acc[4 + mi][ni] = __builtin_amdgcn_mfma_f32_16x16x32_bf16(
            af[mi], bv[ni], acc[4 + mi][ni], 0, 0, 0);
  }

  // Epilogue: C/D layout col=lane&15, row=(lane>>4)*4+reg.
  const int col = lane & 15;
  const int quad = lane >> 4;
  const int m0 = tm << 8;
  const int n0 = tn << 8;
#pragma unroll
  for (int ni = 0; ni < 4; ++ni) {
    const int n = n0 + wn * 64 + ni * 16 + col;
    const float bvs = bias[n];
#pragma unroll
    for (int mi = 0; mi < 8; ++mi) {
      const size_t rowBase = (size_t)(m0 + wm * 128 + mi * 16 + quad * 4) * N + n;
#pragma unroll
      for (int r = 0; r < 4; ++r)
        Out[rowBase + (size_t)r * N] = acc[mi][ni][r] + bvs;
    }
  }
}

// ===========================================================================
// Round-3 fallback paths (P2 / P3), unchanged.
// ===========================================================================
#define BM 128
#define BN 128
#define BK 32

__global__ void foldcast_w_kernel(const float* __restrict__ W,
                                  const float* __restrict__ A,   // [R,K]
                                  const float* __restrict__ Bl,  // [N,R]
                                  __hip_bfloat16* __restrict__ Wp, int K) {
  const int n = blockIdx.y;
  const int k = blockIdx.x * 256 + threadIdx.x;
  float acc = W[(size_t)n * K + k];
#pragma unroll
  for (int r = 0; r < LORA_R; ++r)
    acc += 2.0f * Bl[n * LORA_R + r] * A[(size_t)r * K + k];
  Wp[(size_t)n * K + k] = __float2bfloat16(acc);
}

__global__ void padb32_kernel(const float* __restrict__ lB,
                              __hip_bfloat16* __restrict__ B32) {
  const int i = blockIdx.x * 256 + threadIdx.x;  // over N*32
  const int n = i >> 5, r = i & 31;
  B32[i] = (r < LORA_R) ? __float2bfloat16(lB[n * LORA_R + r])
                        : __float2bfloat16(0.0f);
}

__global__ __launch_bounds__(256) void xa_fp32_kernel(
    const float* __restrict__ X, const float* __restrict__ A,
    __hip_bfloat16* __restrict__ XA32, int K) {
  const int lane = threadIdx.x & 63;
  const int m = blockIdx.x * 4 + (threadIdx.x >> 6);
  float acc[LORA_R] = {};
  const size_t xrow = (size_t)m * K;
  for (int k0 = 0; k0 < K; k0 += 256) {
    const int k = k0 + lane * 4;
    f32x4 xv = *(const f32x4*)(X + xrow + k);
#pragma unroll
    for (int r = 0; r < LORA_R; ++r) {
      f32x4 av = *(const f32x4*)(A + (size_t)r * K + k);
      acc[r] += xv[0] * av[0] + xv[1] * av[1] + xv[2] * av[2] + xv[3] * av[3];
    }
  }
#pragma unroll
  for (int r = 0; r < LORA_R; ++r)
    for (int off = 32; off > 0; off >>= 1) acc[r] += __shfl_xor(acc[r], off, 64);
  if (lane == 0) {
#pragma unroll
    for (int r = 0; r < LORA_R; ++r)
      XA32[(size_t)m * 32 + r] = __float2bfloat16(acc[r]);
#pragma unroll
    for (int r = LORA_R; r < 32; ++r)
      XA32[(size_t)m * 32 + r] = __float2bfloat16(0.0f);
  }
}

template <bool XPRE, bool WPRE, bool ELORA>
__global__ __launch_bounds__(256) void gemm_kernel(
    const void* __restrict__ Xv, const void* __restrict__ Wv,
    const float* __restrict__ bias,
    const __hip_bfloat16* __restrict__ XA32,  // [M,32] zero-padded (ELORA)
    const __hip_bfloat16* __restrict__ B32,   // [N,32] zero-padded (ELORA)
    float* __restrict__ Out, int M, int N, int K) {
  __shared__ __align__(16) unsigned short As[BM * BK];
  __shared__ __align__(16) unsigned short Bs[BN * BK];

  const int t = threadIdx.x;
  const int lane = t & 63;
  const int wave = t >> 6;
  const int m0 = blockIdx.y * BM;
  const int n0 = blockIdx.x * BN;
  const int wm = (wave >> 1) * 64;
  const int wn = (wave & 1) * 64;

  const int srow = t >> 2;
  const int ka = (t & 3) * 8;
  const int f_r = t >> 3;
  const int f_c = (t & 7) * 4;

  char* smA = (char*)As;
  char* smB = (char*)Bs;
  const int waveByte = wave * 1024;

  f32x4 acc[4][4];
#pragma unroll
  for (int mi = 0; mi < 4; ++mi)
#pragma unroll
    for (int ni = 0; ni < 4; ++ni) acc[mi][ni] = (f32x4){0.f, 0.f, 0.f, 0.f};

  const unsigned short* aBase = As + (wm + (lane & 15)) * BK + (lane >> 4) * 8;
  const unsigned short* bBase = Bs + (wn + (lane & 15)) * BK + (lane >> 4) * 8;

  const int kIters = K / BK;
  for (int kt = 0; kt < kIters; ++kt) {
    const int gk = kt * BK;
    if constexpr (XPRE) {
      const __hip_bfloat16* Xb = (const __hip_bfloat16*)Xv;
      async_copy16(Xb + (size_t)(m0 + srow) * K + gk + ka, smA + waveByte);
      async_copy16(Xb + (size_t)(m0 + 64 + srow) * K + gk + ka, smA + 4096 + waveByte);
    } else {
      const float* Xf = (const float*)Xv;
#pragma unroll
      for (int j = 0; j < 4; ++j) {
        const int row = j * 32 + f_r;
        f32x4 v = *(const f32x4*)(Xf + (size_t)(m0 + row) * K + gk + f_c);
        bf16x4 p;
#pragma unroll
        for (int e = 0; e < 4; ++e) p[e] = (__bf16)v[e];
        *(bf16x4*)(smA + row * 64 + f_c * 2) = p;
      }
    }
    if constexpr (WPRE) {
      const __hip_bfloat16* Wb = (const __hip_bfloat16*)Wv;
      async_copy16(Wb + (size_t)(n0 + srow) * K + gk + ka, smB + waveByte);
      async_copy16(Wb + (size_t)(n0 + 64 + srow) * K + gk + ka, smB + 4096 + waveByte);
    } else {
      const float* Wf = (const float*)Wv;
#pragma unroll
      for (int j = 0; j < 4; ++j) {
        const int row = j * 32 + f_r;
        f32x4 v = *(const f32x4*)(Wf + (size_t)(n0 + row) * K + gk + f_c);
        bf16x4 p;
#pragma unroll
        for (int e = 0; e < 4; ++e) p[e] = (__bf16)v[e];
        *(bf16x4*)(smB + row * 64 + f_c * 2) = p;
      }
    }
    __syncthreads();

    bf16x8 af[4], bfv[4];
#pragma unroll
    for (int i = 0; i < 4; ++i) {
      af[i] = *(const bf16x8*)(aBase + i * 16 * BK);
      bfv[i] = *(const bf16x8*)(bBase + i * 16 * BK);
    }
#pragma unroll
    for (int mi = 0; mi < 4; ++mi)
#pragma unroll
      for (int ni = 0; ni < 4; ++ni)
        acc[mi][ni] = __builtin_amdgcn_mfma_f32_16x16x32_bf16(
            af[mi], bfv[ni], acc[mi][ni], 0, 0, 0);
    __syncthreads();
  }

  const int col = lane & 15;
  const int quad = lane >> 4;
  const int rbase = quad * 4;

  bf16x8 xaf[4], blf[4];
  if constexpr (ELORA) {
#pragma unroll
    for (int mi = 0; mi < 4; ++mi)
      xaf[mi] = *(const bf16x8*)(XA32 + (size_t)(m0 + wm + mi * 16 + col) * 32 + quad * 8);
#pragma unroll
    for (int ni = 0; ni < 4; ++ni)
      blf[ni] = *(const bf16x8*)(B32 + (size_t)(n0 + wn + ni * 16 + col) * 32 + quad * 8);
  }

  const f32x4 zero4 = (f32x4){0.f, 0.f, 0.f, 0.f};
#pragma unroll
  for (int ni = 0; ni < 4; ++ni) {
    const int n = n0 + wn + ni * 16 + col;
    const float bv = bias[n];
#pragma unroll
    for (int mi = 0; mi < 4; ++mi) {
      f32x4 u = zero4;
      if constexpr (ELORA)
        u = __builtin_amdgcn_mfma_f32_16x16x32_bf16(xaf[mi], blf[ni], zero4, 0, 0, 0);
      const size_t rowBase = (size_t)(m0 + wm + mi * 16 + rbase) * N + n;
#pragma unroll
      for (int r = 0; r < 4; ++r)
        Out[rowBase + (size_t)r * N] = acc[mi][ni][r] + bv + 2.0f * u[r];
    }
  }
}

// ---------------------------------------------------------------------------
extern "C" void kernel_launch(void* const* d_in, const int* in_sizes, int n_in,
                              void* d_out, int out_size, void* d_ws, size_t ws_size,
                              hipStream_t stream) {
  const float* X    = (const float*)d_in[0];  // [B,S,Din] fp32
  const float* W    = (const float*)d_in[1];  // [Dout,Din] fp32
  const float* bias = (const float*)d_in[2];  // [Dout] fp32
  const float* lA   = (const float*)d_in[3];  // [R,Din] fp32
  const float* lB   = (const float*)d_in[4];  // [Dout,R] fp32
  float* Out = (float*)d_out;

  const int K = in_sizes[3] / LORA_R;  // 4096
  const int N = in_sizes[2];           // 4096
  const int M = in_sizes[0] / K;       // 8192

  const size_t xbBytes = (size_t)M * K * 2;  // 67,108,864
  const size_t wpBytes = (size_t)N * K * 2;  // 33,554,432

  if (ws_size >= xbBytes + wpBytes) {
    // P1: packed precast X and fold+cast W', pipelined 256^2 GEMM.
    __hip_bfloat16* Xp = (__hip_bfloat16*)d_ws;
    __hip_bfloat16* Wq = (__hip_bfloat16*)((char*)d_ws + xbBytes);
    pack_x_kernel<<<dim3(K / 128, M / 16), 256, 0, stream>>>(X, Xp, K);
    foldpack_w_kernel<<<dim3(K / 128, N / 16), 256, 0, stream>>>(W, lA, lB, Wq, K);
    gemm_pipelined<<<dim3((M / 256) * (N / 256)), 512, 0, stream>>>(
        Xp, Wq, bias, Out, M, N, K);
  } else if (ws_size >= wpBytes) {
    // P2: fold+cast W' only (row-major); convert X tiles in-kernel.
    __hip_bfloat16* Wp = (__hip_bfloat16*)d_ws;
    foldcast_w_kernel<<<dim3(K / 256, N), 256, 0, stream>>>(W, lA, lB, Wp, K);
    gemm_kernel<false, true, false><<<dim3(N / BN, M / BM), 256, 0, stream>>>(
        X, Wp, bias, nullptr, nullptr, Out, M, N, K);
  } else {
    // P3: tiny ws — LoRA via epilogue MFMA, both operands converted in-kernel.
    __hip_bfloat16* XA32 = (__hip_bfloat16*)d_ws;           // M*32*2 = 512 KB
    __hip_bfloat16* B32  = XA32 + (size_t)M * 32;           // N*32*2 = 256 KB
    padb32_kernel<<<dim3((N * 32) / 256), 256, 0, stream>>>(lB, B32);
    xa_fp32_kernel<<<dim3(M / 4), 256, 0, stream>>>(X, lA, XA32, K);
    gemm_kernel<false, false, true><<<dim3(N / BN, M / BM), 256, 0, stream>>>(
        X, W, bias, XA32, B32, Out, M, N, K);
  }
}

// Round 2
// 519.677 us; speedup vs baseline: 1.2611x; 1.0108x over previous
//
#include <hip/hip_runtime.h>
#include <hip/hip_bf16.h>
#include <stdint.h>

// ---------------------------------------------------------------------------
// LoRALinear (fp32 in / fp32 out):
//   C[M,N] = X[M,K] @ W[N,K]^T + bias[N] + 2.0 * (X @ A[R,K]^T) @ B[N,R]^T
// M=8192, N=4096, K=4096, R=16.
//
// Round-5: round-4's 256^2 pipeline measured MfmaUtil 45%, conflicts 0.
// Analysis: per K-tile per block, MFMA pipe = 1178 cyc, CU-shared LDS pipe
// = ~857-1129 cyc -> equal pipes, but phase structure (reads -> lgkm(0) ->
// MFMA) serializes them. Fix: one-phase register lookahead with COUNTED
// lgkmcnt(4/8) (never 0 in loop), one barrier per phase (2/tile, each
// preceded by the exact vmcnt/lgkm wait that makes it sufficient).
// Buffer-overwrite invariant (4-deep, distance 3) unchanged.
// ---------------------------------------------------------------------------

typedef __bf16 bf16x8 __attribute__((ext_vector_type(8)));
typedef __bf16 bf16x4 __attribute__((ext_vector_type(4)));
typedef float f32x4 __attribute__((ext_vector_type(4)));

#define LORA_R 16

__device__ __forceinline__ void async_copy16(const void* g, void* l) {
  __builtin_amdgcn_global_load_lds(
      (const __attribute__((address_space(1))) void*)g,
      (__attribute__((address_space(3))) void*)l, 16, 0, 0);
}

// ---------------------------------------------------------------------------
// Packed operand layout: 16x32 blocks, block (rb,kb) at (rb*(K/32)+kb)*1024 B.
// Lane l's 16 B = row rb*16+(l&15), k = kb*32+(l>>4)*8 .. +7  (MFMA A/B frag).
// ---------------------------------------------------------------------------
__global__ __launch_bounds__(256) void pack_x_kernel(
    const float* __restrict__ X, __hip_bfloat16* __restrict__ Xp, int K) {
  const int lane = threadIdx.x & 63;
  const int wave = threadIdx.x >> 6;
  const int nkb = K >> 5;
  const int kb = blockIdx.x * 4 + wave;
  const int mb = blockIdx.y;
  const int row = (mb << 4) + (lane & 15);
  const int col = (kb << 5) + ((lane >> 4) << 3);
  const float* src = X + (size_t)row * K + col;
  f32x4 v0 = *(const f32x4*)src;
  f32x4 v1 = *(const f32x4*)(src + 4);
  bf16x8 o;
#pragma unroll
  for (int j = 0; j < 4; ++j) { o[j] = (__bf16)v0[j]; o[4 + j] = (__bf16)v1[j]; }
  *(bf16x8*)((char*)Xp + ((size_t)(mb * nkb + kb) << 10) + (lane << 4)) = o;
}

__global__ __launch_bounds__(256) void foldpack_w_kernel(
    const float* __restrict__ W, const float* __restrict__ A,
    const float* __restrict__ Bl, __hip_bfloat16* __restrict__ Wp, int K) {
  const int lane = threadIdx.x & 63;
  const int wave = threadIdx.x >> 6;
  const int nkb = K >> 5;
  const int kb = blockIdx.x * 4 + wave;
  const int nb = blockIdx.y;
  const int n = (nb << 4) + (lane & 15);
  const int col = (kb << 5) + ((lane >> 4) << 3);
  float res[8];
  {
    f32x4 w0 = *(const f32x4*)(W + (size_t)n * K + col);
    f32x4 w1 = *(const f32x4*)(W + (size_t)n * K + col + 4);
#pragma unroll
    for (int j = 0; j < 4; ++j) { res[j] = w0[j]; res[4 + j] = w1[j]; }
  }
#pragma unroll
  for (int r = 0; r < LORA_R; ++r) {
    const float b2 = 2.0f * Bl[n * LORA_R + r];  // SCALING = 2.0
    f32x4 a0 = *(const f32x4*)(A + (size_t)r * K + col);
    f32x4 a1 = *(const f32x4*)(A + (size_t)r * K + col + 4);
#pragma unroll
    for (int j = 0; j < 4; ++j) { res[j] += b2 * a0[j]; res[4 + j] += b2 * a1[j]; }
  }
  bf16x8 o;
#pragma unroll
  for (int j = 0; j < 8; ++j) o[j] = (__bf16)res[j];
  *(bf16x8*)((char*)Wp + ((size_t)(nb * nkb + kb) << 10) + (lane << 4)) = o;
}

// ---------------------------------------------------------------------------
// Pipelined 256x256 GEMM, 8 waves (2M x 4N), per-wave 128x64, BK=32.
// ---------------------------------------------------------------------------
#define RD_A4(v0, v1, v2, v3, OFF)                                            \
  v0 = *(const bf16x8*)(ldsRdA + (OFF));                                      \
  v1 = *(const bf16x8*)(ldsRdA + (OFF) + 1024);                               \
  v2 = *(const bf16x8*)(ldsRdA + (OFF) + 2048);                               \
  v3 = *(const bf16x8*)(ldsRdA + (OFF) + 3072);

#define RD_B4(v0, v1, v2, v3, OFF)                                            \
  v0 = *(const bf16x8*)(ldsRdB + (OFF));                                      \
  v1 = *(const bf16x8*)(ldsRdB + (OFF) + 1024);                               \
  v2 = *(const bf16x8*)(ldsRdB + (OFF) + 2048);                               \
  v3 = *(const bf16x8*)(ldsRdB + (OFF) + 3072);

#define MFMA16(BASE, A0, A1, A2, A3, B0, B1, B2, B3)                          \
  acc[BASE + 0][0] = __builtin_amdgcn_mfma_f32_16x16x32_bf16(A0, B0, acc[BASE + 0][0], 0, 0, 0); \
  acc[BASE + 0][1] = __builtin_amdgcn_mfma_f32_16x16x32_bf16(A0, B1, acc[BASE + 0][1], 0, 0, 0); \
  acc[BASE + 0][2] = __builtin_amdgcn_mfma_f32_16x16x32_bf16(A0, B2, acc[BASE + 0][2], 0, 0, 0); \
  acc[BASE + 0][3] = __builtin_amdgcn_mfma_f32_16x16x32_bf16(A0, B3, acc[BASE + 0][3], 0, 0, 0); \
  acc[BASE + 1][0] = __builtin_amdgcn_mfma_f32_16x16x32_bf16(A1, B0, acc[BASE + 1][0], 0, 0, 0); \
  acc[BASE + 1][1] = __builtin_amdgcn_mfma_f32_16x16x32_bf16(A1, B1, acc[BASE + 1][1], 0, 0, 0); \
  acc[BASE + 1][2] = __builtin_amdgcn_mfma_f32_16x16x32_bf16(A1, B2, acc[BASE + 1][2], 0, 0, 0); \
  acc[BASE + 1][3] = __builtin_amdgcn_mfma_f32_16x16x32_bf16(A1, B3, acc[BASE + 1][3], 0, 0, 0); \
  acc[BASE + 2][0] = __builtin_amdgcn_mfma_f32_16x16x32_bf16(A2, B0, acc[BASE + 2][0], 0, 0, 0); \
  acc[BASE + 2][1] = __builtin_amdgcn_mfma_f32_16x16x32_bf16(A2, B1, acc[BASE + 2][1], 0, 0, 0); \
  acc[BASE + 2][2] = __builtin_amdgcn_mfma_f32_16x16x32_bf16(A2, B2, acc[BASE + 2][2], 0, 0, 0); \
  acc[BASE + 2][3] = __builtin_amdgcn_mfma_f32_16x16x32_bf16(A2, B3, acc[BASE + 2][3], 0, 0, 0); \
  acc[BASE + 3][0] = __builtin_amdgcn_mfma_f32_16x16x32_bf16(A3, B0, acc[BASE + 3][0], 0, 0, 0); \
  acc[BASE + 3][1] = __builtin_amdgcn_mfma_f32_16x16x32_bf16(A3, B1, acc[BASE + 3][1], 0, 0, 0); \
  acc[BASE + 3][2] = __builtin_amdgcn_mfma_f32_16x16x32_bf16(A3, B2, acc[BASE + 3][2], 0, 0, 0); \
  acc[BASE + 3][3] = __builtin_amdgcn_mfma_f32_16x16x32_bf16(A3, B3, acc[BASE + 3][3], 0, 0, 0);

#define STAGE_A(T3, SLOT)                                                     \
  async_copy16(aSrc + ((size_t)(T3) << 10), ldsA + (SLOT));                   \
  async_copy16(aSrc + siteStride + ((size_t)(T3) << 10), ldsA + (SLOT) + 8192);

#define STAGE_B(T3, SLOT)                                                     \
  async_copy16(bSrc + ((size_t)(T3) << 10), ldsB + (SLOT));                   \
  async_copy16(bSrc + siteStride + ((size_t)(T3) << 10), ldsB + (SLOT) + 8192);

#define SBAR() __builtin_amdgcn_sched_barrier(0)

__global__ __launch_bounds__(512, 2) void gemm_pipelined(
    const __hip_bfloat16* __restrict__ Xp,  // packed [M/16][K/32] blocks
    const __hip_bfloat16* __restrict__ Wp,  // packed [N/16][K/32] blocks
    const float* __restrict__ bias,
    float* __restrict__ Out, int M, int N, int K) {
  __shared__ __align__(16) char lds[131072];

  const int tid = threadIdx.x;
  const int lane = tid & 63;
  const int wave = tid >> 6;
  const int wm = wave >> 2;  // 0..1
  const int wn = wave & 3;   // 0..3

  // Bijective XCD-aware swizzle (gridDim.x = 512, % 8 == 0).
  const int nwg = gridDim.x;
  const int bid = blockIdx.x;
  const int swz = (bid & 7) * (nwg >> 3) + (bid >> 3);
  const int ntn = N >> 8;  // 16
  const int tm = swz / ntn;
  const int tn = swz - tm * ntn;

  const int nkb = K >> 5;  // 128 K-tiles
  const int nt = nkb;

  const char* aSrc = (const char*)Xp +
      ((size_t)((tm << 4) + wave) * nkb << 10) + (lane << 4);
  const char* bSrc = (const char*)Wp +
      ((size_t)((tn << 4) + wave) * nkb << 10) + (lane << 4);
  const size_t siteStride = (size_t)8 * nkb << 10;

  char* ldsA = lds + (wave << 10);
  char* ldsB = lds + 16384 + (wave << 10);
  const char* ldsRdA = lds + (wm << 13) + (lane << 4);
  const char* ldsRdB = lds + 16384 + (wn << 12) + (lane << 4);

  f32x4 acc[8][4];
#pragma unroll
  for (int i = 0; i < 8; ++i)
#pragma unroll
    for (int j = 0; j < 4; ++j) acc[i][j] = (f32x4){0.f, 0.f, 0.f, 0.f};

  // Prologue: stage tiles 0,1,2 into bufs 0,1,2.
#pragma unroll
  for (int pt = 0; pt < 3; ++pt) {
    const int bo = pt << 15;
    async_copy16(aSrc + ((size_t)pt << 10), ldsA + bo);
    async_copy16(aSrc + siteStride + ((size_t)pt << 10), ldsA + bo + 8192);
    async_copy16(bSrc + ((size_t)pt << 10), ldsB + bo);
    async_copy16(bSrc + siteStride + ((size_t)pt << 10), ldsB + bo + 8192);
  }
  asm volatile("s_waitcnt vmcnt(8)" ::: "memory");  // tile 0 landed
  __builtin_amdgcn_s_barrier();
  SBAR();

  // Operand register sets: E/O = tile-parity double buffer; a1 = frags 4-7,
  // single-buffered (consumed each p1, reloaded next p0).
  bf16x8 aE0, aE1, aE2, aE3, aO0, aO1, aO2, aO3, a10, a11, a12, a13;
  bf16x8 bE0, bE1, bE2, bE3, bO0, bO1, bO2, bO3;

  // Preload tile 0 phase-0 regs.
  RD_A4(aE0, aE1, aE2, aE3, 0);
  RD_B4(bE0, bE1, bE2, bE3, 0);

  for (int e = 0; e + 5 <= nt; e += 2) {
    const int ofsE = (e & 3) << 15;
    const int ofsO = ((e + 1) & 3) << 15;
    const int ofsN = ((e + 2) & 3) << 15;
    const int s3 = ((e + 3) & 3) << 15;
    const int s4 = ((e + 4) & 3) << 15;

    // ---- p0(e): consume aE x bE; lookahead a1(e); stage A(e+3) ----
    RD_A4(a10, a11, a12, a13, ofsE + 4096);
    STAGE_A(e + 3, s3);
    asm volatile("s_waitcnt lgkmcnt(4)" ::: "memory");  // aE,bE ready
    SBAR();
    __builtin_amdgcn_s_setprio(1);
    MFMA16(0, aE0, aE1, aE2, aE3, bE0, bE1, bE2, bE3);
    __builtin_amdgcn_s_setprio(0);
    asm volatile("s_waitcnt vmcnt(6)" ::: "memory");  // tile e+1 landed
    __builtin_amdgcn_s_barrier();
    SBAR();

    // ---- p1(e): consume a1 x bE; lookahead aO,bO (buf e+1); stage B(e+3) --
    RD_A4(aO0, aO1, aO2, aO3, ofsO);
    RD_B4(bO0, bO1, bO2, bO3, ofsO);
    STAGE_B(e + 3, s3);
    asm volatile("s_waitcnt lgkmcnt(8)" ::: "memory");  // a1 ready
    SBAR();
    __builtin_amdgcn_s_setprio(1);
    MFMA16(4, a10, a11, a12, a13, bE0, bE1, bE2, bE3);
    __builtin_amdgcn_s_setprio(0);
    __builtin_amdgcn_s_barrier();
    SBAR();

    // ---- p0(o): consume aO x bO; lookahead a1(o); stage A(e+4) ----
    RD_A4(a10, a11, a12, a13, ofsO + 4096);
    STAGE_A(e + 4, s4);
    asm volatile("s_waitcnt lgkmcnt(4)" ::: "memory");  // aO,bO ready
    SBAR();
    __builtin_amdgcn_s_setprio(1);
    MFMA16(0, aO0, aO1, aO2, aO3, bO0, bO1, bO2, bO3);
    __builtin_amdgcn_s_setprio(0);
    asm volatile("s_waitcnt vmcnt(6)" ::: "memory");  // tile e+2 landed
    __builtin_amdgcn_s_barrier();
    SBAR();

    // ---- p1(o): consume a1 x bO; lookahead aE,bE (buf e+2); stage B(e+4) --
    RD_A4(aE0, aE1, aE2, aE3, ofsN);
    RD_B4(bE0, bE1, bE2, bE3, ofsN);
    STAGE_B(e + 4, s4);
    asm volatile("s_waitcnt lgkmcnt(8)" ::: "memory");  // a1 ready
    SBAR();
    __builtin_amdgcn_s_setprio(1);
    MFMA16(4, a10, a11, a12, a13, bO0, bO1, bO2, bO3);
    __builtin_amdgcn_s_setprio(0);
    __builtin_amdgcn_s_barrier();
    SBAR();
  }

  // Drain: stage last tile (slot of fully-consumed tile nt-5), then compute
  // tiles nt-4..nt-1 plainly (compiler-managed waits; no staging in flight).
  {
    const int tL = nt - 1;
    const int sL = (tL & 3) << 15;
    STAGE_A(tL, sL);
    STAGE_B(tL, sL);
    asm volatile("s_waitcnt vmcnt(0)" ::: "memory");
    __builtin_amdgcn_s_barrier();
    SBAR();
    for (int t = nt - 4; t < nt; ++t) {
      const int ofs = (t & 3) << 15;
      bf16x8 af[8], bv4[4];
#pragma unroll
      for (int i = 0; i < 8; ++i)
        af[i] = *(const bf16x8*)(ldsRdA + ofs + (i << 10));
#pragma unroll
      for (int i = 0; i < 4; ++i)
        bv4[i] = *(const bf16x8*)(ldsRdB + ofs + (i << 10));
#pragma unroll
      for (int mi = 0; mi < 8; ++mi)
#pragma unroll
        for (int ni = 0; ni < 4; ++ni)
          acc[mi][ni] = __builtin_amdgcn_mfma_f32_16x16x32_bf16(
              af[mi], bv4[ni], acc[mi][ni], 0, 0, 0);
    }
  }

  // Epilogue: C/D layout col=lane&15, row=(lane>>4)*4+reg.
  const int col = lane & 15;
  const int quad = lane >> 4;
  const int m0 = tm << 8;
  const int n0 = tn << 8;
#pragma unroll
  for (int ni = 0; ni < 4; ++ni) {
    const int n = n0 + wn * 64 + ni * 16 + col;
    const float bvs = bias[n];
#pragma unroll
    for (int mi = 0; mi < 8; ++mi) {
      const size_t rowBase = (size_t)(m0 + wm * 128 + mi * 16 + quad * 4) * N + n;
#pragma unroll
      for (int r = 0; r < 4; ++r)
        Out[rowBase + (size_t)r * N] = acc[mi][ni][r] + bvs;
    }
  }
}

// ===========================================================================
// Fallback paths (P2 / P3), unchanged.
// ===========================================================================
#define BM 128
#define BN 128
#define BK 32

__global__ void foldcast_w_kernel(const float* __restrict__ W,
                                  const float* __restrict__ A,   // [R,K]
                                  const float* __restrict__ Bl,  // [N,R]
                                  __hip_bfloat16* __restrict__ Wp, int K) {
  const int n = blockIdx.y;
  const int k = blockIdx.x * 256 + threadIdx.x;
  float acc = W[(size_t)n * K + k];
#pragma unroll
  for (int r = 0; r < LORA_R; ++r)
    acc += 2.0f * Bl[n * LORA_R + r] * A[(size_t)r * K + k];
  Wp[(size_t)n * K + k] = __float2bfloat16(acc);
}

__global__ void padb32_kernel(const float* __restrict__ lB,
                              __hip_bfloat16* __restrict__ B32) {
  const int i = blockIdx.x * 256 + threadIdx.x;  // over N*32
  const int n = i >> 5, r = i & 31;
  B32[i] = (r < LORA_R) ? __float2bfloat16(lB[n * LORA_R + r])
                        : __float2bfloat16(0.0f);
}

__global__ __launch_bounds__(256) void xa_fp32_kernel(
    const float* __restrict__ X, const float* __restrict__ A,
    __hip_bfloat16* __restrict__ XA32, int K) {
  const int lane = threadIdx.x & 63;
  const int m = blockIdx.x * 4 + (threadIdx.x >> 6);
  float acc[LORA_R] = {};
  const size_t xrow = (size_t)m * K;
  for (int k0 = 0; k0 < K; k0 += 256) {
    const int k = k0 + lane * 4;
    f32x4 xv = *(const f32x4*)(X + xrow + k);
#pragma unroll
    for (int r = 0; r < LORA_R; ++r) {
      f32x4 av = *(const f32x4*)(A + (size_t)r * K + k);
      acc[r] += xv[0] * av[0] + xv[1] * av[1] + xv[2] * av[2] + xv[3] * av[3];
    }
  }
#pragma unroll
  for (int r = 0; r < LORA_R; ++r)
    for (int off = 32; off > 0; off >>= 1) acc[r] += __shfl_xor(acc[r], off, 64);
  if (lane == 0) {
#pragma unroll
    for (int r = 0; r < LORA_R; ++r)
      XA32[(size_t)m * 32 + r] = __float2bfloat16(acc[r]);
#pragma unroll
    for (int r = LORA_R; r < 32; ++r)
      XA32[(size_t)m * 32 + r] = __float2bfloat16(0.0f);
  }
}

template <bool XPRE, bool WPRE, bool ELORA>
__global__ __launch_bounds__(256) void gemm_kernel(
    const void* __restrict__ Xv, const void* __restrict__ Wv,
    const float* __restrict__ bias,
    const __hip_bfloat16* __restrict__ XA32,  // [M,32] zero-padded (ELORA)
    const __hip_bfloat16* __restrict__ B32,   // [N,32] zero-padded (ELORA)
    float* __restrict__ Out, int M, int N, int K) {
  __shared__ __align__(16) unsigned short As[BM * BK];
  __shared__ __align__(16) unsigned short Bs[BN * BK];

  const int t = threadIdx.x;
  const int lane = t & 63;
  const int wave = t >> 6;
  const int m0 = blockIdx.y * BM;
  const int n0 = blockIdx.x * BN;
  const int wm = (wave >> 1) * 64;
  const int wn = (wave & 1) * 64;

  const int srow = t >> 2;
  const int ka = (t & 3) * 8;
  const int f_r = t >> 3;
  const int f_c = (t & 7) * 4;

  char* smA = (char*)As;
  char* smB = (char*)Bs;
  const int waveByte = wave * 1024;

  f32x4 acc[4][4];
#pragma unroll
  for (int mi = 0; mi < 4; ++mi)
#pragma unroll
    for (int ni = 0; ni < 4; ++ni) acc[mi][ni] = (f32x4){0.f, 0.f, 0.f, 0.f};

  const unsigned short* aBase = As + (wm + (lane & 15)) * BK + (lane >> 4) * 8;
  const unsigned short* bBase = Bs + (wn + (lane & 15)) * BK + (lane >> 4) * 8;

  const int kIters = K / BK;
  for (int kt = 0; kt < kIters; ++kt) {
    const int gk = kt * BK;
    if constexpr (XPRE) {
      const __hip_bfloat16* Xb = (const __hip_bfloat16*)Xv;
      async_copy16(Xb + (size_t)(m0 + srow) * K + gk + ka, smA + waveByte);
      async_copy16(Xb + (size_t)(m0 + 64 + srow) * K + gk + ka, smA + 4096 + waveByte);
    } else {
      const float* Xf = (const float*)Xv;
#pragma unroll
      for (int j = 0; j < 4; ++j) {
        const int row = j * 32 + f_r;
        f32x4 v = *(const f32x4*)(Xf + (size_t)(m0 + row) * K + gk + f_c);
        bf16x4 p;
#pragma unroll
        for (int e = 0; e < 4; ++e) p[e] = (__bf16)v[e];
        *(bf16x4*)(smA + row * 64 + f_c * 2) = p;
      }
    }
    if constexpr (WPRE) {
      const __hip_bfloat16* Wb = (const __hip_bfloat16*)Wv;
      async_copy16(Wb + (size_t)(n0 + srow) * K + gk + ka, smB + waveByte);
      async_copy16(Wb + (size_t)(n0 + 64 + srow) * K + gk + ka, smB + 4096 + waveByte);
    } else {
      const float* Wf = (const float*)Wv;
#pragma unroll
      for (int j = 0; j < 4; ++j) {
        const int row = j * 32 + f_r;
        f32x4 v = *(const f32x4*)(Wf + (size_t)(n0 + row) * K + gk + f_c);
        bf16x4 p;
#pragma unroll
        for (int e = 0; e < 4; ++e) p[e] = (__bf16)v[e];
        *(bf16x4*)(smB + row * 64 + f_c * 2) = p;
      }
    }
    __syncthreads();

    bf16x8 af[4], bfv[4];
#pragma unroll
    for (int i = 0; i < 4; ++i) {
      af[i] = *(const bf16x8*)(aBase + i * 16 * BK);
      bfv[i] = *(const bf16x8*)(bBase + i * 16 * BK);
    }
#pragma unroll
    for (int mi = 0; mi < 4; ++mi)
#pragma unroll
      for (int ni = 0; ni < 4; ++ni)
        acc[mi][ni] = __builtin_amdgcn_mfma_f32_16x16x32_bf16(
            af[mi], bfv[ni], acc[mi][ni], 0, 0, 0);
    __syncthreads();
  }

  const int col = lane & 15;
  const int quad = lane >> 4;
  const int rbase = quad * 4;

  bf16x8 xaf[4], blf[4];
  if constexpr (ELORA) {
#pragma unroll
    for (int mi = 0; mi < 4; ++mi)
      xaf[mi] = *(const bf16x8*)(XA32 + (size_t)(m0 + wm + mi * 16 + col) * 32 + quad * 8);
#pragma unroll
    for (int ni = 0; ni < 4; ++ni)
      blf[ni] = *(const bf16x8*)(B32 + (size_t)(n0 + wn + ni * 16 + col) * 32 + quad * 8);
  }

  const f32x4 zero4 = (f32x4){0.f, 0.f, 0.f, 0.f};
#pragma unroll
  for (int ni = 0; ni < 4; ++ni) {
    const int n = n0 + wn + ni * 16 + col;
    const float bv = bias[n];
#pragma unroll
    for (int mi = 0; mi < 4; ++mi) {
      f32x4 u = zero4;
      if constexpr (ELORA)
        u = __builtin_amdgcn_mfma_f32_16x16x32_bf16(xaf[mi], blf[ni], zero4, 0, 0, 0);
      const size_t rowBase = (size_t)(m0 + wm + mi * 16 + rbase) * N + n;
#pragma unroll
      for (int r = 0; r < 4; ++r)
        Out[rowBase + (size_t)r * N] = acc[mi][ni][r] + bv + 2.0f * u[r];
    }
  }
}

// ---------------------------------------------------------------------------
extern "C" void kernel_launch(void* const* d_in, const int* in_sizes, int n_in,
                              void* d_out, int out_size, void* d_ws, size_t ws_size,
                              hipStream_t stream) {
  const float* X    = (const float*)d_in[0];  // [B,S,Din] fp32
  const float* W    = (const float*)d_in[1];  // [Dout,Din] fp32
  const float* bias = (const float*)d_in[2];  // [Dout] fp32
  const float* lA   = (const float*)d_in[3];  // [R,Din] fp32
  const float* lB   = (const float*)d_in[4];  // [Dout,R] fp32
  float* Out = (float*)d_out;

  const int K = in_sizes[3] / LORA_R;  // 4096
  const int N = in_sizes[2];           // 4096
  const int M = in_sizes[0] / K;       // 8192

  const size_t xbBytes = (size_t)M * K * 2;  // 67,108,864
  const size_t wpBytes = (size_t)N * K * 2;  // 33,554,432

  if (ws_size >= xbBytes + wpBytes) {
    // P1: packed precast X and fold+cast W', pipelined 256^2 GEMM.
    __hip_bfloat16* Xp = (__hip_bfloat16*)d_ws;
    __hip_bfloat16* Wq = (__hip_bfloat16*)((char*)d_ws + xbBytes);
    pack_x_kernel<<<dim3(K / 128, M / 16), 256, 0, stream>>>(X, Xp, K);
    foldpack_w_kernel<<<dim3(K / 128, N / 16), 256, 0, stream>>>(W, lA, lB, Wq, K);
    gemm_pipelined<<<dim3((M / 256) * (N / 256)), 512, 0, stream>>>(
        Xp, Wq, bias, Out, M, N, K);
  } else if (ws_size >= wpBytes) {
    // P2: fold+cast W' only (row-major); convert X tiles in-kernel.
    __hip_bfloat16* Wp = (__hip_bfloat16*)d_ws;
    foldcast_w_kernel<<<dim3(K / 256, N), 256, 0, stream>>>(W, lA, lB, Wp, K);
    gemm_kernel<false, true, false><<<dim3(N / BN, M / BM), 256, 0, stream>>>(
        X, Wp, bias, nullptr, nullptr, Out, M, N, K);
  } else {
    // P3: tiny ws — LoRA via epilogue MFMA, both operands converted in-kernel.
    __hip_bfloat16* XA32 = (__hip_bfloat16*)d_ws;           // M*32*2 = 512 KB
    __hip_bfloat16* B32  = XA32 + (size_t)M * 32;           // N*32*2 = 256 KB
    padb32_kernel<<<dim3((N * 32) / 256), 256, 0, stream>>>(lB, B32);
    xa_fp32_kernel<<<dim3(M / 4), 256, 0, stream>>>(X, lA, XA32, K);
    gemm_kernel<false, false, true><<<dim3(N / BN, M / BM), 256, 0, stream>>>(
        X, W, bias, XA32, B32, Out, M, N, K);
  }
}